// Round 8
// baseline (130.074 us; speedup 1.0000x reference)
//
#include <hip/hip_runtime.h>
#include <hip/hip_bf16.h>
#include <stdint.h>

typedef __bf16 bf16;
typedef __bf16 bf16x8 __attribute__((ext_vector_type(8)));
typedef float f32x4 __attribute__((ext_vector_type(4)));
typedef float f32x16 __attribute__((ext_vector_type(16)));
typedef unsigned int u32;
typedef u32 u32x4 __attribute__((ext_vector_type(4)));

#define D_MODEL 1024
#define S_LEN 2048
#define NB 2
#define NH 16
#define DH 64

__device__ __forceinline__ void gload_lds16(const bf16* g, bf16* l) {
    auto gp = reinterpret_cast<const __attribute__((address_space(1))) unsigned int*>(
        reinterpret_cast<uintptr_t>(g));
    auto lp = reinterpret_cast<__attribute__((address_space(3))) unsigned int*>(
        reinterpret_cast<uintptr_t>(l));
    __builtin_amdgcn_global_load_lds(gp, lp, 16, 0, 0);
}

__device__ __forceinline__ u32 cvtpk(float lo, float hi) {
    u32 r; asm("v_cvt_pk_bf16_f32 %0, %1, %2" : "=v"(r) : "v"(lo), "v"(hi)); return r;
}
// NOTE: only safe when a and b hold DISTINCT values (else regalloc may coalesce
// the two tied operands into one register -> self-swap). See round-7 post-mortem.
__device__ __forceinline__ void plswap(u32& a, u32& b) {
    asm("v_permlane32_swap_b32 %0, %1" : "+v"(a), "+v"(b));
}

// ---------------- f32 -> bf16 converter: q,k,v (4M each) + 4 weights (1M each) ------
__global__ __launch_bounds__(256)
void cvt_all(const float* __restrict__ q, const float* __restrict__ k,
             const float* __restrict__ v, const float* __restrict__ w0,
             const float* __restrict__ w1, const float* __restrict__ w2,
             const float* __restrict__ w3,
             bf16* __restrict__ oq, bf16* __restrict__ ok, bf16* __restrict__ ov,
             bf16* __restrict__ o0, bf16* __restrict__ o1, bf16* __restrict__ o2,
             bf16* __restrict__ o3)
{
    const int bid = blockIdx.x;
    const float* in; bf16* out; int local;
    if (bid < 6144) {
        int r = bid >> 11; local = bid & 2047;
        in  = (r == 0) ? q  : (r == 1) ? k  : v;
        out = (r == 0) ? oq : (r == 1) ? ok : ov;
    } else {
        int wb = bid - 6144;
        int r = wb >> 9; local = wb & 511;
        in  = (r == 0) ? w0 : (r == 1) ? w1 : (r == 2) ? w2 : w3;
        out = (r == 0) ? o0 : (r == 1) ? o1 : (r == 2) ? o2 : o3;
    }
    const size_t i = ((size_t)local * 256 + threadIdx.x) * 8;
    f32x4 x = *(const f32x4*)(in + i);
    f32x4 y = *(const f32x4*)(in + i + 4);
    bf16x8 o;
    #pragma unroll
    for (int j = 0; j < 4; ++j) { o[j] = (bf16)x[j]; o[4 + j] = (bf16)y[j]; }
    *(bf16x8*)(out + i) = o;
}

// ---------------- Fused QKV GEMM: three C = A_sel @ W_sel^T + b_sel ----------------
// M=4096, N=3072 (Q|K|V), K=1024. BM=128,BN=64,BK=64. V output goes transposed to VT.
__global__ __launch_bounds__(256)
void gemm_qkv(const bf16* __restrict__ Aq, const bf16* __restrict__ Ak, const bf16* __restrict__ Av,
              const bf16* __restrict__ Wq, const bf16* __restrict__ Wk, const bf16* __restrict__ Wv,
              const float* __restrict__ bq, const float* __restrict__ bk, const float* __restrict__ bv,
              bf16* __restrict__ Qo, bf16* __restrict__ Ko, bf16* __restrict__ VTo, float qscale)
{
    __shared__ __align__(16) bf16 As[2][128 * 64];
    __shared__ __align__(16) bf16 Bs[2][64 * 64];

    const int K = 1024;
    const int t = threadIdx.x, lane = t & 63, wid = t >> 6;
    const int nbn = 48;
    const int cpx = gridDim.x >> 3;          // 192
    const int bid = blockIdx.x;
    const int swz = (bid & 7) * cpx + (bid >> 3);
    const int bm0 = (swz / nbn) << 7;
    const int bn0 = (swz % nbn) << 6;
    const int sel = bn0 >> 10;               // 0=Q 1=K 2=V
    const int nl  = bn0 & 1023;
    const bf16* Ap = (sel == 0) ? Aq : (sel == 1) ? Ak : Av;
    const bf16* Bp = (sel == 0) ? Wq : (sel == 1) ? Wk : Wv;
    const float* bias = (sel == 0) ? bq : (sel == 1) ? bk : bv;

    const int r16 = lane & 15, g = lane >> 4;
    const int wr = (wid >> 1) << 6;
    const int wc = (wid & 1) << 5;

    f32x4 acc[4][2] = {};

    auto stage = [&](int buf, int k0) {
        #pragma unroll
        for (int i = 0; i < 4; ++i) {
            int ch = wid * 256 + i * 64 + lane;
            int row = ch >> 3, c8 = ch & 7;
            int sc = c8 ^ (row & 7);
            gload_lds16(Ap + (size_t)(bm0 + row) * K + k0 + sc * 8, &As[buf][ch * 8]);
        }
        #pragma unroll
        for (int i = 0; i < 2; ++i) {
            int ch = wid * 128 + i * 64 + lane;
            int row = ch >> 3, c8 = ch & 7;
            int sc = c8 ^ (row & 7);
            gload_lds16(Bp + (size_t)(nl + row) * K + k0 + sc * 8, &Bs[buf][ch * 8]);
        }
    };

    int cur = 0;
    stage(0, 0);
    for (int k0 = 0; k0 < K; k0 += 64) {
        __syncthreads();
        if (k0 + 64 < K) stage(cur ^ 1, k0 + 64);
        #pragma unroll
        for (int ks = 0; ks < 2; ++ks) {
            const int cl = ks * 4 + g;
            bf16x8 af[4], bfr[2];
            #pragma unroll
            for (int mi = 0; mi < 4; ++mi) {
                int row = wr + mi * 16 + r16;
                af[mi] = *(const bf16x8*)((const char*)&As[cur][0] + row * 128 + ((cl ^ (row & 7)) << 4));
            }
            #pragma unroll
            for (int ni = 0; ni < 2; ++ni) {
                int row = wc + ni * 16 + r16;
                bfr[ni] = *(const bf16x8*)((const char*)&Bs[cur][0] + row * 128 + ((cl ^ (row & 7)) << 4));
            }
            #pragma unroll
            for (int mi = 0; mi < 4; ++mi)
                #pragma unroll
                for (int ni = 0; ni < 2; ++ni)
                    acc[mi][ni] = __builtin_amdgcn_mfma_f32_16x16x32_bf16(af[mi], bfr[ni], acc[mi][ni], 0, 0, 0);
        }
        cur ^= 1;
    }

    const int rb = g * 4;
    if (sel == 2) {
        // V: write transposed VT[b*16+h][d][s]
        __syncthreads();
        bf16* Ts = (bf16*)&As[0][0];
        #pragma unroll
        for (int mi = 0; mi < 4; ++mi)
            #pragma unroll
            for (int ni = 0; ni < 2; ++ni) {
                int dl = wc + ni * 16 + r16;
                float bv = bias[nl + dl];
                #pragma unroll
                for (int r = 0; r < 4; ++r) {
                    int sl = wr + mi * 16 + rb + r;
                    Ts[dl * 136 + sl] = (bf16)(acc[mi][ni][r] + bv);
                }
            }
        __syncthreads();
        const int bq2 = bm0 >> 11, hq = nl >> 6, s0 = bm0 & 2047;
        #pragma unroll
        for (int i2 = 0; i2 < 4; ++i2) {
            int ch = t + i2 * 256;
            int d = ch >> 4, sc = ch & 15;
            bf16x8 v = *(const bf16x8*)&Ts[d * 136 + sc * 8];
            *(bf16x8*)(VTo + ((size_t)(bq2 * 16 + hq) * 64 + d) * S_LEN + s0 + sc * 8) = v;
        }
    } else {
        bf16* out = sel ? Ko : Qo;
        const float cs = sel ? 1.0f : qscale;
        #pragma unroll
        for (int mi = 0; mi < 4; ++mi) {
            #pragma unroll
            for (int ni = 0; ni < 2; ++ni) {
                int cg = nl + wc + ni * 16 + r16;
                float bv = bias[cg];
                #pragma unroll
                for (int r = 0; r < 4; ++r) {
                    int rg = bm0 + wr + mi * 16 + rb + r;
                    out[(size_t)rg * 1024 + cg] = (bf16)((acc[mi][ni][r] + bv) * cs);
                }
            }
        }
    }
}

// ---------------- O-projection GEMM (f32 out) ----------------
__global__ __launch_bounds__(256)
void gemm_out(const bf16* __restrict__ Ap, const bf16* __restrict__ Bp,
              const float* __restrict__ bias, float* __restrict__ Cp)
{
    __shared__ __align__(16) bf16 As[2][128 * 64];
    __shared__ __align__(16) bf16 Bs[2][64 * 64];

    const int K = 1024, N = 1024;
    const int t = threadIdx.x, lane = t & 63, wid = t >> 6;
    const int nbn = 16;
    const int cpx = gridDim.x >> 3;
    const int bid = blockIdx.x;
    const int swz = (bid & 7) * cpx + (bid >> 3);
    const int bm0 = (swz / nbn) << 7;
    const int bn0 = (swz % nbn) << 6;
    const int r16 = lane & 15, g = lane >> 4;
    const int wr = (wid >> 1) << 6;
    const int wc = (wid & 1) << 5;

    f32x4 acc[4][2] = {};

    auto stage = [&](int buf, int k0) {
        #pragma unroll
        for (int i = 0; i < 4; ++i) {
            int ch = wid * 256 + i * 64 + lane;
            int row = ch >> 3, c8 = ch & 7;
            int sc = c8 ^ (row & 7);
            gload_lds16(Ap + (size_t)(bm0 + row) * K + k0 + sc * 8, &As[buf][ch * 8]);
        }
        #pragma unroll
        for (int i = 0; i < 2; ++i) {
            int ch = wid * 128 + i * 64 + lane;
            int row = ch >> 3, c8 = ch & 7;
            int sc = c8 ^ (row & 7);
            gload_lds16(Bp + (size_t)(bn0 + row) * K + k0 + sc * 8, &Bs[buf][ch * 8]);
        }
    };

    int cur = 0;
    stage(0, 0);
    for (int k0 = 0; k0 < K; k0 += 64) {
        __syncthreads();
        if (k0 + 64 < K) stage(cur ^ 1, k0 + 64);
        #pragma unroll
        for (int ks = 0; ks < 2; ++ks) {
            const int cl = ks * 4 + g;
            bf16x8 af[4], bfr[2];
            #pragma unroll
            for (int mi = 0; mi < 4; ++mi) {
                int row = wr + mi * 16 + r16;
                af[mi] = *(const bf16x8*)((const char*)&As[cur][0] + row * 128 + ((cl ^ (row & 7)) << 4));
            }
            #pragma unroll
            for (int ni = 0; ni < 2; ++ni) {
                int row = wc + ni * 16 + r16;
                bfr[ni] = *(const bf16x8*)((const char*)&Bs[cur][0] + row * 128 + ((cl ^ (row & 7)) << 4));
            }
            #pragma unroll
            for (int mi = 0; mi < 4; ++mi)
                #pragma unroll
                for (int ni = 0; ni < 2; ++ni)
                    acc[mi][ni] = __builtin_amdgcn_mfma_f32_16x16x32_bf16(af[mi], bfr[ni], acc[mi][ni], 0, 0, 0);
        }
        cur ^= 1;
    }

    const int rb = g * 4;
    #pragma unroll
    for (int mi = 0; mi < 4; ++mi) {
        #pragma unroll
        for (int ni = 0; ni < 2; ++ni) {
            int cg = bn0 + wc + ni * 16 + r16;
            float bv = bias[cg];
            #pragma unroll
            for (int r = 0; r < 4; ++r) {
                int rg = bm0 + wr + mi * 16 + rb + r;
                Cp[(size_t)rg * N + cg] = acc[mi][ni][r] + bv;
            }
        }
    }
}

// ---------------- Flash attention v7b: block split-K x2 + dynamic LPT --------------
// 1024 blocks = 32bh x 16qt x 2kh. Block = 4 waves x 32 q-rows (128-row tile qt);
// k-half kh processes qt+1 KT=64 tiles. Partials (O^T bf16, m, l) to workspace.
// Cross-pair reductions via __shfl_xor(x,32) (round-6-proven; the permlane variant
// hit a register-coalescing hazard in round 7). Defer-rescale when max stable.
__global__ __launch_bounds__(256, 3)
void attn7(const bf16* __restrict__ Qp, const bf16* __restrict__ Kp,
           const bf16* __restrict__ VTp, bf16* __restrict__ Pws, float* __restrict__ MLws)
{
    __shared__ __align__(16) char smem[2][16384];   // [buf][K 8KB | V 8KB]

    const int t = threadIdx.x, lane = t & 63, qs = t >> 6;
    const int l31 = lane & 31, hh = lane >> 5;

    const int bid = blockIdx.x;
    const int xcd = bid & 7, s = bid >> 3;           // s 0..127 per XCD
    const int bh = xcd * 4 + (s >> 5);
    const int kh = (s >> 4) & 1;
    const int im = s & 15, g2 = im >> 2, r4 = im & 3;
    const int qt = (r4 == 0) ? 15 - g2 : (r4 == 1) ? 7 - g2 : (r4 == 2) ? g2 : 8 + g2;
    const int b = bh >> 4, h = bh & 15;

    const size_t base = (size_t)b * (S_LEN * D_MODEL) + h * DH;
    const size_t vtbase = (size_t)bh * (DH * S_LEN);

    const int q0b = qt * 128;
    const int q0w = q0b + qs * 32;
    const int rounds = qt + 1;
    const int tbase = kh ? (qt + 1) : 0;
    const int teff = 2 * qt + (qs >> 1) + 1;         // first fully-masked global tile

    auto stage = [&](int buf, int tt) {
        char* kb = smem[buf];
        char* vb = kb + 8192;
        #pragma unroll
        for (int p = 0; p < 2; ++p) {
            int ch = t + p * 256;                    // 0..511
            int row = ch >> 3, c8 = ch & 7;
            int so = (c8 ^ (row & 7)) << 3;
            gload_lds16(Kp + base + (size_t)(tt * 64 + row) * D_MODEL + so, (bf16*)(kb + ch * 16));
            gload_lds16(VTp + vtbase + (size_t)row * S_LEN + tt * 64 + so, (bf16*)(vb + ch * 16));
        }
    };

    bf16x8 qf[4];
    {
        const bf16* qrow = Qp + base + (size_t)(q0w + l31) * D_MODEL + hh * 8;
        #pragma unroll
        for (int db = 0; db < 4; ++db) qf[db] = *(const bf16x8*)(qrow + db * 16);
    }

    f32x16 oacc[2] = {};
    float mx = -1e30f, lsum = 0.f;

    int cur = 0;
    stage(0, tbase);
    #pragma unroll 1
    for (int r = 0; r < rounds; ++r) {
        __syncthreads();                             // buf[cur] staged
        if (r + 1 < rounds) stage(cur ^ 1, tbase + r + 1);
        const int tt = tbase + r;
        if (tt < teff) {
            const char* kbp = smem[cur];
            const char* vbp = kbp + 8192;
            f32x16 sacc[2] = {};
            __builtin_amdgcn_s_setprio(1);
            #pragma unroll
            for (int ks = 0; ks < 2; ++ks) {
                int row = ks * 32 + l31;
                #pragma unroll
                for (int db = 0; db < 4; ++db) {
                    int c = db * 2 + hh;
                    bf16x8 kf = *(const bf16x8*)(kbp + row * 128 + ((c ^ (row & 7)) << 4));
                    sacc[ks] = __builtin_amdgcn_mfma_f32_32x32x16_bf16(kf, qf[db], sacc[ks], 0, 0, 0);
                }
            }
            __builtin_amdgcn_s_setprio(0);
            if (tt == teff - 1) {                    // diagonal tile
                const int thr = q0w + l31 - 4 * hh - tt * 64;
                #pragma unroll
                for (int ks = 0; ks < 2; ++ks)
                    #pragma unroll
                    for (int r2 = 0; r2 < 16; ++r2) {
                        const int cr = 32 * ks + (r2 & 3) + 8 * (r2 >> 2);
                        if (cr > thr) sacc[ks][r2] = -1e9f;
                    }
            }
            float pm = -3e38f;
            #pragma unroll
            for (int ks = 0; ks < 2; ++ks)
                #pragma unroll
                for (int r2 = 0; r2 < 16; ++r2) pm = fmaxf(pm, sacc[ks][r2]);
            pm = fmaxf(pm, __shfl_xor(pm, 32));
            if (__any(pm > mx)) {
                float mnew = fmaxf(mx, pm);
                float al = __builtin_exp2f(mx - mnew);
                lsum *= al;
                #pragma unroll
                for (int dt = 0; dt < 2; ++dt)
                    #pragma unroll
                    for (int r2 = 0; r2 < 16; ++r2) oacc[dt][r2] *= al;
                mx = mnew;
            }
            float ts = 0.f;
            #pragma unroll
            for (int ks = 0; ks < 2; ++ks)
                #pragma unroll
                for (int r2 = 0; r2 < 16; ++r2) {
                    float p = __builtin_exp2f(sacc[ks][r2] - mx);
                    sacc[ks][r2] = p;
                    ts += p;
                }
            lsum += ts + __shfl_xor(ts, 32);

            #pragma unroll
            for (int kb2 = 0; kb2 < 4; ++kb2) {
                const int ks = kb2 >> 1, rb2 = (kb2 & 1) * 8;
                u32 w0 = cvtpk(sacc[ks][rb2 + 0], sacc[ks][rb2 + 1]);
                u32 w2 = cvtpk(sacc[ks][rb2 + 4], sacc[ks][rb2 + 5]);
                u32 w1 = cvtpk(sacc[ks][rb2 + 2], sacc[ks][rb2 + 3]);
                u32 w3 = cvtpk(sacc[ks][rb2 + 6], sacc[ks][rb2 + 7]);
                plswap(w0, w2);
                plswap(w1, w3);
                u32x4 pw; pw[0] = w0; pw[1] = w1; pw[2] = w2; pw[3] = w3;
                bf16x8 pb = __builtin_bit_cast(bf16x8, pw);
                __builtin_amdgcn_s_setprio(1);
                #pragma unroll
                for (int dt = 0; dt < 2; ++dt) {
                    int row = dt * 32 + l31, c = kb2 * 2 + hh;
                    bf16x8 vfr = *(const bf16x8*)(vbp + row * 128 + ((c ^ (row & 7)) << 4));
                    oacc[dt] = __builtin_amdgcn_mfma_f32_32x32x16_bf16(vfr, pb, oacc[dt], 0, 0, 0);
                }
                __builtin_amdgcn_s_setprio(0);
            }
        }
        cur ^= 1;
    }

    // ---- write partials: Pws[bid][q=128][d=64] bf16 (unnormalized), MLws[bid][2][128]
    bf16* pb = Pws + (size_t)bid * 8192;
    const int qrow = qs * 32 + l31;
    #pragma unroll
    for (int dt = 0; dt < 2; ++dt)
        #pragma unroll
        for (int r2 = 0; r2 < 16; r2 += 2) {
            int d = dt * 32 + (r2 & 3) + 8 * (r2 >> 2) + 4 * hh;
            *(u32*)(pb + qrow * 64 + d) = cvtpk(oacc[dt][r2], oacc[dt][r2 + 1]);
        }
    if (hh == 0) {
        MLws[(size_t)bid * 256 + qrow] = mx;
        MLws[(size_t)bid * 256 + 128 + qrow] = lsum;
    }
}

// ---------------- split-K merge: combine the two k-half partials -> Ob -------------
__global__ __launch_bounds__(256)
void attn_merge(const bf16* __restrict__ Pws, const float* __restrict__ MLws,
                bf16* __restrict__ Ob)
{
    const int mb = blockIdx.x;               // 512 = 32bh x 16qt
    const int bh = mb >> 4, qt = mb & 15;
    const int xcd = bh >> 2;
    int i;
    if (qt >= 12)      i = (15 - qt) * 4;
    else if (qt >= 8)  i = (qt - 8) * 4 + 3;
    else if (qt >= 4)  i = (7 - qt) * 4 + 1;
    else               i = qt * 4 + 2;
    const int sA = (bh & 3) * 32 + i;
    const int bidA = sA * 8 + xcd;
    const int bidB = (sA + 16) * 8 + xcd;
    const int b = bh >> 4, h = bh & 15;

    const int t = threadIdx.x;
    const int q = t >> 1, dh = t & 1;        // q 0..127, d-half 0..1
    const float mA = MLws[(size_t)bidA * 256 + q], lA = MLws[(size_t)bidA * 256 + 128 + q];
    const float mB = MLws[(size_t)bidB * 256 + q], lB = MLws[(size_t)bidB * 256 + 128 + q];
    const float m = fmaxf(mA, mB);
    float a0 = __builtin_exp2f(mA - m), a1 = __builtin_exp2f(mB - m);
    const float linv = 1.0f / (lA * a0 + lB * a1);
    a0 *= linv; a1 *= linv;
    const bf16* pA = Pws + (size_t)bidA * 8192 + q * 64 + dh * 32;
    const bf16* pB = Pws + (size_t)bidB * 8192 + q * 64 + dh * 32;
    bf16* op = Ob + (size_t)(b * S_LEN + qt * 128 + q) * D_MODEL + h * DH + dh * 32;
    #pragma unroll
    for (int j = 0; j < 4; ++j) {
        bf16x8 va = *(const bf16x8*)(pA + j * 8);
        bf16x8 vb = *(const bf16x8*)(pB + j * 8);
        bf16x8 o;
        #pragma unroll
        for (int e = 0; e < 8; ++e)
            o[e] = (bf16)(a0 * (float)va[e] + a1 * (float)vb[e]);
        *(bf16x8*)(op + j * 8) = o;
    }
}

extern "C" void kernel_launch(void* const* d_in, const int* in_sizes, int n_in,
                              void* d_out, int out_size, void* d_ws, size_t ws_size,
                              hipStream_t stream)
{
    const float* query = (const float*)d_in[0];
    const float* key   = (const float*)d_in[1];
    const float* value = (const float*)d_in[2];
    // d_in[3] = mask: structurally causal (triu k=1) -> applied analytically
    const float* W_q = (const float*)d_in[4];
    const float* b_q = (const float*)d_in[5];
    const float* W_k = (const float*)d_in[6];
    const float* b_k = (const float*)d_in[7];
    const float* W_v = (const float*)d_in[8];
    const float* b_v = (const float*)d_in[9];
    const float* W_o = (const float*)d_in[10];
    const float* b_o = (const float*)d_in[11];

    char* w = (char*)d_ws;
    const size_t MB = 1 << 20;
    // [0,8) qbf | [8,16) kbf | [16,24) vbf   (dead after gemm_qkv)
    // [24,32) Qb | [32,40) Kb | [40,48) VT | [48,56) weights
    // attn7 partials overlay dead zone: Pws [0,16), MLws [16,17); merge writes Ob [17,25)
    bf16* qbf = (bf16*)(w);
    bf16* kbf = (bf16*)(w + 8 * MB);
    bf16* vbf = (bf16*)(w + 16 * MB);
    bf16* Qb  = (bf16*)(w + 24 * MB);         // pre-scaled by 0.125*log2(e)
    bf16* Kb  = (bf16*)(w + 32 * MB);
    bf16* VT  = (bf16*)(w + 40 * MB);
    bf16* Wqb = (bf16*)(w + 48 * MB);
    bf16* Wkb = (bf16*)(w + 50 * MB);
    bf16* Wvb = (bf16*)(w + 52 * MB);
    bf16* Wob = (bf16*)(w + 54 * MB);
    bf16*  Pws  = (bf16*)(w);                 // 16MB
    float* MLws = (float*)(w + 16 * MB);      // 1MB
    bf16*  Ob   = (bf16*)(w + 17 * MB);       // 8MB (over vbf tail + Qb head, both dead)

    dim3 blk(256);
    cvt_all<<<dim3(8192), blk, 0, stream>>>(query, key, value, W_q, W_k, W_v, W_o,
                                            qbf, kbf, vbf, Wqb, Wkb, Wvb, Wob);

    const float qscale = 0.125f * 1.4426950408889634f;   // 1/sqrt(64) * log2(e)
    gemm_qkv<<<dim3(1536), blk, 0, stream>>>(qbf, kbf, vbf, Wqb, Wkb, Wvb,
                                             b_q, b_k, b_v, Qb, Kb, VT, qscale);

    attn7<<<dim3(1024), blk, 0, stream>>>(Qb, Kb, VT, Pws, MLws);
    attn_merge<<<dim3(512), blk, 0, stream>>>(Pws, MLws, Ob);

    gemm_out<<<dim3(512), blk, 0, stream>>>(Ob, Wob, b_o, (float*)d_out);
}

// Round 9
// 112.550 us; speedup vs baseline: 1.1557x; 1.1557x over previous
//
#include <hip/hip_runtime.h>
#include <hip/hip_bf16.h>
#include <stdint.h>

typedef __bf16 bf16;
typedef __bf16 bf16x8 __attribute__((ext_vector_type(8)));
typedef float f32x4 __attribute__((ext_vector_type(4)));
typedef float f32x16 __attribute__((ext_vector_type(16)));
typedef unsigned int u32;
typedef u32 u32x4 __attribute__((ext_vector_type(4)));

#define D_MODEL 1024
#define S_LEN 2048
#define NB 2
#define NH 16
#define DH 64

__device__ __forceinline__ void gload_lds16(const bf16* g, bf16* l) {
    auto gp = reinterpret_cast<const __attribute__((address_space(1))) unsigned int*>(
        reinterpret_cast<uintptr_t>(g));
    auto lp = reinterpret_cast<__attribute__((address_space(3))) unsigned int*>(
        reinterpret_cast<uintptr_t>(l));
    __builtin_amdgcn_global_load_lds(gp, lp, 16, 0, 0);
}

__device__ __forceinline__ u32 cvtpk(float lo, float hi) {
    u32 r; asm("v_cvt_pk_bf16_f32 %0, %1, %2" : "=v"(r) : "v"(lo), "v"(hi)); return r;
}
// NOTE: only safe when a and b hold DISTINCT values (round-7 post-mortem:
// identical tied operands may be register-coalesced -> self-swap).
__device__ __forceinline__ void plswap(u32& a, u32& b) {
    asm("v_permlane32_swap_b32 %0, %1" : "+v"(a), "+v"(b));
}

// ---------------- f32 -> bf16 converter: q,k,v (4M each) + 4 weights (1M each) ------
__global__ __launch_bounds__(256)
void cvt_all(const float* __restrict__ q, const float* __restrict__ k,
             const float* __restrict__ v, const float* __restrict__ w0,
             const float* __restrict__ w1, const float* __restrict__ w2,
             const float* __restrict__ w3,
             bf16* __restrict__ oq, bf16* __restrict__ ok, bf16* __restrict__ ov,
             bf16* __restrict__ o0, bf16* __restrict__ o1, bf16* __restrict__ o2,
             bf16* __restrict__ o3)
{
    const int bid = blockIdx.x;
    const float* in; bf16* out; int local;
    if (bid < 6144) {
        int r = bid >> 11; local = bid & 2047;
        in  = (r == 0) ? q  : (r == 1) ? k  : v;
        out = (r == 0) ? oq : (r == 1) ? ok : ov;
    } else {
        int wb = bid - 6144;
        int r = wb >> 9; local = wb & 511;
        in  = (r == 0) ? w0 : (r == 1) ? w1 : (r == 2) ? w2 : w3;
        out = (r == 0) ? o0 : (r == 1) ? o1 : (r == 2) ? o2 : o3;
    }
    const size_t i = ((size_t)local * 256 + threadIdx.x) * 8;
    f32x4 x = *(const f32x4*)(in + i);
    f32x4 y = *(const f32x4*)(in + i + 4);
    bf16x8 o;
    #pragma unroll
    for (int j = 0; j < 4; ++j) { o[j] = (bf16)x[j]; o[4 + j] = (bf16)y[j]; }
    *(bf16x8*)(out + i) = o;
}

// ---------------- Fused QKV GEMM, 128x128 tile: C = A_sel @ W_sel^T + b_sel --------
// M=4096, N=3072 (Q|K|V), K=1024. BM=128,BN=128,BK=64. 4 waves 2x2, wave = 64x64.
// V output written transposed to VT[b*16+h][d][s] via LDS.
__global__ __launch_bounds__(256, 2)
void gemm_qkv2(const bf16* __restrict__ Aq, const bf16* __restrict__ Ak, const bf16* __restrict__ Av,
               const bf16* __restrict__ Wq, const bf16* __restrict__ Wk, const bf16* __restrict__ Wv,
               const float* __restrict__ bq, const float* __restrict__ bk, const float* __restrict__ bv,
               bf16* __restrict__ Qo, bf16* __restrict__ Ko, bf16* __restrict__ VTo, float qscale)
{
    __shared__ __align__(16) char gsm[65536];    // As[2][8K elems] | Bs[2][8K elems]
    bf16* As = (bf16*)gsm;
    bf16* Bs = (bf16*)(gsm + 32768);

    const int K = 1024;
    const int t = threadIdx.x, lane = t & 63, wid = t >> 6;
    const int nbn = 24;
    const int cpx = gridDim.x >> 3;              // 96
    const int bid = blockIdx.x;
    const int swz = (bid & 7) * cpx + (bid >> 3);
    const int bm0 = (swz / nbn) << 7;
    const int bn0 = (swz % nbn) << 7;
    const int sel = bn0 >> 10;                   // 0=Q 1=K 2=V
    const int nl  = bn0 & 1023;
    const bf16* Ap = (sel == 0) ? Aq : (sel == 1) ? Ak : Av;
    const bf16* Bp = (sel == 0) ? Wq : (sel == 1) ? Wk : Wv;
    const float* bias = (sel == 0) ? bq : (sel == 1) ? bk : bv;

    const int r16 = lane & 15, g = lane >> 4;
    const int wr = (wid >> 1) << 6;              // 0 or 64
    const int wc = (wid & 1) << 6;               // 0 or 64

    f32x4 acc[4][4] = {};

    auto stage = [&](int buf, int k0) {
        #pragma unroll
        for (int i = 0; i < 4; ++i) {
            int ch = wid * 256 + i * 64 + lane;  // 0..1023
            int row = ch >> 3, c8 = ch & 7;
            int sc = c8 ^ (row & 7);
            gload_lds16(Ap + (size_t)(bm0 + row) * K + k0 + sc * 8, As + buf * 8192 + ch * 8);
            gload_lds16(Bp + (size_t)(nl + row) * K + k0 + sc * 8, Bs + buf * 8192 + ch * 8);
        }
    };

    int cur = 0;
    stage(0, 0);
    for (int k0 = 0; k0 < K; k0 += 64) {
        __syncthreads();
        if (k0 + 64 < K) stage(cur ^ 1, k0 + 64);
        #pragma unroll
        for (int ks = 0; ks < 2; ++ks) {
            const int cl = ks * 4 + g;
            bf16x8 af[4], bfr[4];
            #pragma unroll
            for (int mi = 0; mi < 4; ++mi) {
                int row = wr + mi * 16 + r16;
                af[mi] = *(const bf16x8*)((const char*)As + cur * 16384 + row * 128 + ((cl ^ (row & 7)) << 4));
            }
            #pragma unroll
            for (int ni = 0; ni < 4; ++ni) {
                int row = wc + ni * 16 + r16;
                bfr[ni] = *(const bf16x8*)((const char*)Bs + cur * 16384 + row * 128 + ((cl ^ (row & 7)) << 4));
            }
            #pragma unroll
            for (int mi = 0; mi < 4; ++mi)
                #pragma unroll
                for (int ni = 0; ni < 4; ++ni)
                    acc[mi][ni] = __builtin_amdgcn_mfma_f32_16x16x32_bf16(af[mi], bfr[ni], acc[mi][ni], 0, 0, 0);
        }
        cur ^= 1;
    }

    const int rb = g * 4;
    if (sel == 2) {
        // V: transpose 128x128 tile via LDS, write VT[b*16+h][d][s]
        __syncthreads();
        bf16* Ts = (bf16*)gsm;                   // [128][136] = 34816B
        #pragma unroll
        for (int mi = 0; mi < 4; ++mi)
            #pragma unroll
            for (int ni = 0; ni < 4; ++ni) {
                int dl = wc + ni * 16 + r16;
                float bv = bias[nl + dl];
                #pragma unroll
                for (int r = 0; r < 4; ++r) {
                    int sl = wr + mi * 16 + rb + r;
                    Ts[dl * 136 + sl] = (bf16)(acc[mi][ni][r] + bv);
                }
            }
        __syncthreads();
        const int bq2 = bm0 >> 11, s0 = bm0 & 2047;
        #pragma unroll
        for (int i2 = 0; i2 < 8; ++i2) {
            int ch = t + i2 * 256;               // 0..2047
            int d = ch >> 4, sc = ch & 15;
            int hg = (nl + d) >> 6, dl2 = (nl + d) & 63;
            bf16x8 v = *(const bf16x8*)&Ts[d * 136 + sc * 8];
            *(bf16x8*)(VTo + ((size_t)(bq2 * 16 + hg) * 64 + dl2) * S_LEN + s0 + sc * 8) = v;
        }
    } else {
        bf16* out = sel ? Ko : Qo;
        const float cs = sel ? 1.0f : qscale;
        #pragma unroll
        for (int mi = 0; mi < 4; ++mi) {
            #pragma unroll
            for (int ni = 0; ni < 4; ++ni) {
                int cg = nl + wc + ni * 16 + r16;
                float bv = bias[cg];
                #pragma unroll
                for (int r = 0; r < 4; ++r) {
                    int rg = bm0 + wr + mi * 16 + rb + r;
                    out[(size_t)rg * 1024 + cg] = (bf16)((acc[mi][ni][r] + bv) * cs);
                }
            }
        }
    }
}

// ---------------- O-projection GEMM (f32 out), BM=128 BN=64 ----------------
__global__ __launch_bounds__(256)
void gemm_out(const bf16* __restrict__ Ap, const bf16* __restrict__ Bp,
              const float* __restrict__ bias, float* __restrict__ Cp)
{
    __shared__ __align__(16) bf16 As[2][128 * 64];
    __shared__ __align__(16) bf16 Bs[2][64 * 64];

    const int K = 1024, N = 1024;
    const int t = threadIdx.x, lane = t & 63, wid = t >> 6;
    const int nbn = 16;
    const int cpx = gridDim.x >> 3;
    const int bid = blockIdx.x;
    const int swz = (bid & 7) * cpx + (bid >> 3);
    const int bm0 = (swz / nbn) << 7;
    const int bn0 = (swz % nbn) << 6;
    const int r16 = lane & 15, g = lane >> 4;
    const int wr = (wid >> 1) << 6;
    const int wc = (wid & 1) << 5;

    f32x4 acc[4][2] = {};

    auto stage = [&](int buf, int k0) {
        #pragma unroll
        for (int i = 0; i < 4; ++i) {
            int ch = wid * 256 + i * 64 + lane;
            int row = ch >> 3, c8 = ch & 7;
            int sc = c8 ^ (row & 7);
            gload_lds16(Ap + (size_t)(bm0 + row) * K + k0 + sc * 8, &As[buf][ch * 8]);
        }
        #pragma unroll
        for (int i = 0; i < 2; ++i) {
            int ch = wid * 128 + i * 64 + lane;
            int row = ch >> 3, c8 = ch & 7;
            int sc = c8 ^ (row & 7);
            gload_lds16(Bp + (size_t)(bn0 + row) * K + k0 + sc * 8, &Bs[buf][ch * 8]);
        }
    };

    int cur = 0;
    stage(0, 0);
    for (int k0 = 0; k0 < K; k0 += 64) {
        __syncthreads();
        if (k0 + 64 < K) stage(cur ^ 1, k0 + 64);
        #pragma unroll
        for (int ks = 0; ks < 2; ++ks) {
            const int cl = ks * 4 + g;
            bf16x8 af[4], bfr[2];
            #pragma unroll
            for (int mi = 0; mi < 4; ++mi) {
                int row = wr + mi * 16 + r16;
                af[mi] = *(const bf16x8*)((const char*)&As[cur][0] + row * 128 + ((cl ^ (row & 7)) << 4));
            }
            #pragma unroll
            for (int ni = 0; ni < 2; ++ni) {
                int row = wc + ni * 16 + r16;
                bfr[ni] = *(const bf16x8*)((const char*)&Bs[cur][0] + row * 128 + ((cl ^ (row & 7)) << 4));
            }
            #pragma unroll
            for (int mi = 0; mi < 4; ++mi)
                #pragma unroll
                for (int ni = 0; ni < 2; ++ni)
                    acc[mi][ni] = __builtin_amdgcn_mfma_f32_16x16x32_bf16(af[mi], bfr[ni], acc[mi][ni], 0, 0, 0);
        }
        cur ^= 1;
    }

    const int rb = g * 4;
    #pragma unroll
    for (int mi = 0; mi < 4; ++mi) {
        #pragma unroll
        for (int ni = 0; ni < 2; ++ni) {
            int cg = bn0 + wc + ni * 16 + r16;
            float bv = bias[cg];
            #pragma unroll
            for (int r = 0; r < 4; ++r) {
                int rg = bm0 + wr + mi * 16 + rb + r;
                Cp[(size_t)rg * N + cg] = acc[mi][ni][r] + bv;
            }
        }
    }
}

// ---------------- Flash attention v8: phase-paired block split-K (uniform work) -----
// 512 blocks = 8xcd x {4bh x 2kh x 8P}. Each block: phases qt={P,15-P}; kh=0 stages
// tiles 0..qt, kh=1 stages qt+1..2qt+1 -> EVERY block stages exactly 17 rounds,
// independent of dispatch mapping. 2 blocks/CU overlap barrier drains (m114).
// Partials (O^T bf16, m, l) to workspace; merge kernel combines kh halves.
__global__ __launch_bounds__(256, 2)
void attn8(const bf16* __restrict__ Qp, const bf16* __restrict__ Kp,
           const bf16* __restrict__ VTp, bf16* __restrict__ Pws, float* __restrict__ MLws)
{
    __shared__ __align__(16) char smem[2][16384];   // [buf][K 8KB | V 8KB]

    const int t = threadIdx.x, lane = t & 63, qs = t >> 6;
    const int l31 = lane & 31, hh = lane >> 5;

    const int bid = blockIdx.x;
    const int xcd = bid & 7, s = bid >> 3;           // s 0..63
    const int bh = xcd * 4 + (s >> 4);
    const int rem = s & 15;
    const int kh = rem >> 3, P = rem & 7;
    const int b = bh >> 4, h = bh & 15;

    const size_t base = (size_t)b * (S_LEN * D_MODEL) + h * DH;
    const size_t vtbase = (size_t)bh * (DH * S_LEN);

    auto stage = [&](int buf, int tt) {
        char* kb = smem[buf];
        char* vb = kb + 8192;
        #pragma unroll
        for (int p = 0; p < 2; ++p) {
            int ch = t + p * 256;                    // 0..511
            int row = ch >> 3, c8 = ch & 7;
            int so = (c8 ^ (row & 7)) << 3;
            gload_lds16(Kp + base + (size_t)(tt * 64 + row) * D_MODEL + so, (bf16*)(kb + ch * 16));
            gload_lds16(VTp + vtbase + (size_t)row * S_LEN + tt * 64 + so, (bf16*)(vb + ch * 16));
        }
    };

    #pragma unroll 1
    for (int ph = 0; ph < 2; ++ph) {
        const int qt = ph ? (15 - P) : P;
        const int q0w = qt * 128 + qs * 32;
        const int nr = qt + 1;                       // rounds this phase
        const int tbase = kh ? (qt + 1) : 0;
        const int teff = 2 * qt + (qs >> 1) + 1;     // first fully-masked global tile

        bf16x8 qf[4];
        {
            const bf16* qrow = Qp + base + (size_t)(q0w + l31) * D_MODEL + hh * 8;
            #pragma unroll
            for (int db = 0; db < 4; ++db) qf[db] = *(const bf16x8*)(qrow + db * 16);
        }

        f32x16 oacc[2] = {};
        float mx = -1e30f, lsum = 0.f;

        if (ph) __syncthreads();                     // previous phase's LDS reads done
        int cur = 0;
        stage(0, tbase);
        #pragma unroll 1
        for (int r = 0; r < nr; ++r) {
            __syncthreads();                         // buf[cur] staged
            if (r + 1 < nr) stage(cur ^ 1, tbase + r + 1);
            const int tt = tbase + r;
            if (tt < teff) {
                const char* kbp = smem[cur];
                const char* vbp = kbp + 8192;
                f32x16 sacc[2] = {};
                __builtin_amdgcn_s_setprio(1);
                #pragma unroll
                for (int ks = 0; ks < 2; ++ks) {
                    int row = ks * 32 + l31;
                    #pragma unroll
                    for (int db = 0; db < 4; ++db) {
                        int c = db * 2 + hh;
                        bf16x8 kf = *(const bf16x8*)(kbp + row * 128 + ((c ^ (row & 7)) << 4));
                        sacc[ks] = __builtin_amdgcn_mfma_f32_32x32x16_bf16(kf, qf[db], sacc[ks], 0, 0, 0);
                    }
                }
                __builtin_amdgcn_s_setprio(0);
                if (tt == teff - 1) {                // diagonal tile
                    const int thr = q0w + l31 - 4 * hh - tt * 64;
                    #pragma unroll
                    for (int ks = 0; ks < 2; ++ks)
                        #pragma unroll
                        for (int r2 = 0; r2 < 16; ++r2) {
                            const int cr = 32 * ks + (r2 & 3) + 8 * (r2 >> 2);
                            if (cr > thr) sacc[ks][r2] = -1e9f;
                        }
                }
                float pm = -3e38f;
                #pragma unroll
                for (int ks = 0; ks < 2; ++ks)
                    #pragma unroll
                    for (int r2 = 0; r2 < 16; ++r2) pm = fmaxf(pm, sacc[ks][r2]);
                pm = fmaxf(pm, __shfl_xor(pm, 32));
                if (__any(pm > mx)) {
                    float mnew = fmaxf(mx, pm);
                    float al = __builtin_exp2f(mx - mnew);
                    lsum *= al;
                    #pragma unroll
                    for (int dt = 0; dt < 2; ++dt)
                        #pragma unroll
                        for (int r2 = 0; r2 < 16; ++r2) oacc[dt][r2] *= al;
                    mx = mnew;
                }
                float ts = 0.f;
                #pragma unroll
                for (int ks = 0; ks < 2; ++ks)
                    #pragma unroll
                    for (int r2 = 0; r2 < 16; ++r2) {
                        float p = __builtin_exp2f(sacc[ks][r2] - mx);
                        sacc[ks][r2] = p;
                        ts += p;
                    }
                lsum += ts + __shfl_xor(ts, 32);

                #pragma unroll
                for (int kb2 = 0; kb2 < 4; ++kb2) {
                    const int ks = kb2 >> 1, rb2 = (kb2 & 1) * 8;
                    u32 w0 = cvtpk(sacc[ks][rb2 + 0], sacc[ks][rb2 + 1]);
                    u32 w2 = cvtpk(sacc[ks][rb2 + 4], sacc[ks][rb2 + 5]);
                    u32 w1 = cvtpk(sacc[ks][rb2 + 2], sacc[ks][rb2 + 3]);
                    u32 w3 = cvtpk(sacc[ks][rb2 + 6], sacc[ks][rb2 + 7]);
                    plswap(w0, w2);
                    plswap(w1, w3);
                    u32x4 pw; pw[0] = w0; pw[1] = w1; pw[2] = w2; pw[3] = w3;
                    bf16x8 pb = __builtin_bit_cast(bf16x8, pw);
                    __builtin_amdgcn_s_setprio(1);
                    #pragma unroll
                    for (int dt = 0; dt < 2; ++dt) {
                        int row = dt * 32 + l31, c = kb2 * 2 + hh;
                        bf16x8 vfr = *(const bf16x8*)(vbp + row * 128 + ((c ^ (row & 7)) << 4));
                        oacc[dt] = __builtin_amdgcn_mfma_f32_32x32x16_bf16(vfr, pb, oacc[dt], 0, 0, 0);
                    }
                    __builtin_amdgcn_s_setprio(0);
                }
            }
            cur ^= 1;
        }

        // ---- write partials: pid = (bh*16+qt)*2+kh; Pws[pid][q=128][d=64], ML[pid][2][128]
        const int pid = (bh * 16 + qt) * 2 + kh;
        bf16* pb = Pws + (size_t)pid * 8192;
        const int qrow = qs * 32 + l31;
        #pragma unroll
        for (int dt = 0; dt < 2; ++dt)
            #pragma unroll
            for (int r2 = 0; r2 < 16; r2 += 2) {
                int d = dt * 32 + (r2 & 3) + 8 * (r2 >> 2) + 4 * hh;
                *(u32*)(pb + qrow * 64 + d) = cvtpk(oacc[dt][r2], oacc[dt][r2 + 1]);
            }
        if (hh == 0) {
            MLws[(size_t)pid * 256 + qrow] = mx;
            MLws[(size_t)pid * 256 + 128 + qrow] = lsum;
        }
    }
}

// ---------------- split-K merge: combine the two k-half partials -> Ob -------------
__global__ __launch_bounds__(256)
void attn_merge(const bf16* __restrict__ Pws, const float* __restrict__ MLws,
                bf16* __restrict__ Ob)
{
    const int mb = blockIdx.x;               // 512 = 32bh x 16qt
    const int bh = mb >> 4, qt = mb & 15;
    const int pidA = (bh * 16 + qt) * 2;
    const int pidB = pidA + 1;
    const int b = bh >> 4, h = bh & 15;

    const int t = threadIdx.x;
    const int q = t >> 1, dh = t & 1;        // q 0..127, d-half 0..1
    const float mA = MLws[(size_t)pidA * 256 + q], lA = MLws[(size_t)pidA * 256 + 128 + q];
    const float mB = MLws[(size_t)pidB * 256 + q], lB = MLws[(size_t)pidB * 256 + 128 + q];
    const float m = fmaxf(mA, mB);
    float a0 = __builtin_exp2f(mA - m), a1 = __builtin_exp2f(mB - m);
    const float linv = 1.0f / (lA * a0 + lB * a1);
    a0 *= linv; a1 *= linv;
    const bf16* pA = Pws + (size_t)pidA * 8192 + q * 64 + dh * 32;
    const bf16* pB = Pws + (size_t)pidB * 8192 + q * 64 + dh * 32;
    bf16* op = Ob + (size_t)(b * S_LEN + qt * 128 + q) * D_MODEL + h * DH + dh * 32;
    #pragma unroll
    for (int j = 0; j < 4; ++j) {
        bf16x8 va = *(const bf16x8*)(pA + j * 8);
        bf16x8 vb = *(const bf16x8*)(pB + j * 8);
        bf16x8 o;
        #pragma unroll
        for (int e = 0; e < 8; ++e)
            o[e] = (bf16)(a0 * (float)va[e] + a1 * (float)vb[e]);
        *(bf16x8*)(op + j * 8) = o;
    }
}

extern "C" void kernel_launch(void* const* d_in, const int* in_sizes, int n_in,
                              void* d_out, int out_size, void* d_ws, size_t ws_size,
                              hipStream_t stream)
{
    const float* query = (const float*)d_in[0];
    const float* key   = (const float*)d_in[1];
    const float* value = (const float*)d_in[2];
    // d_in[3] = mask: structurally causal (triu k=1) -> applied analytically
    const float* W_q = (const float*)d_in[4];
    const float* b_q = (const float*)d_in[5];
    const float* W_k = (const float*)d_in[6];
    const float* b_k = (const float*)d_in[7];
    const float* W_v = (const float*)d_in[8];
    const float* b_v = (const float*)d_in[9];
    const float* W_o = (const float*)d_in[10];
    const float* b_o = (const float*)d_in[11];

    char* w = (char*)d_ws;
    const size_t MB = 1 << 20;
    // [0,8) qbf | [8,16) kbf | [16,24) vbf   (dead after gemm_qkv2)
    // [24,32) Qb | [32,40) Kb | [40,48) VT | [48,56) weights
    // attn8 partials overlay dead zone: Pws [0,16), MLws [16,17); merge writes Ob [17,25)
    bf16* qbf = (bf16*)(w);
    bf16* kbf = (bf16*)(w + 8 * MB);
    bf16* vbf = (bf16*)(w + 16 * MB);
    bf16* Qb  = (bf16*)(w + 24 * MB);         // pre-scaled by 0.125*log2(e)
    bf16* Kb  = (bf16*)(w + 32 * MB);
    bf16* VT  = (bf16*)(w + 40 * MB);
    bf16* Wqb = (bf16*)(w + 48 * MB);
    bf16* Wkb = (bf16*)(w + 50 * MB);
    bf16* Wvb = (bf16*)(w + 52 * MB);
    bf16* Wob = (bf16*)(w + 54 * MB);
    bf16*  Pws  = (bf16*)(w);                 // 16MB
    float* MLws = (float*)(w + 16 * MB);      // 1MB
    bf16*  Ob   = (bf16*)(w + 17 * MB);       // 8MB (over vbf tail + Qb head, both dead)

    dim3 blk(256);
    cvt_all<<<dim3(8192), blk, 0, stream>>>(query, key, value, W_q, W_k, W_v, W_o,
                                            qbf, kbf, vbf, Wqb, Wkb, Wvb, Wob);

    const float qscale = 0.125f * 1.4426950408889634f;   // 1/sqrt(64) * log2(e)
    gemm_qkv2<<<dim3(768), blk, 0, stream>>>(qbf, kbf, vbf, Wqb, Wkb, Wvb,
                                             b_q, b_k, b_v, Qb, Kb, VT, qscale);

    attn8<<<dim3(512), blk, 0, stream>>>(Qb, Kb, VT, Pws, MLws);
    attn_merge<<<dim3(512), blk, 0, stream>>>(Pws, MLws, Ob);

    gemm_out<<<dim3(512), blk, 0, stream>>>(Ob, Wob, b_o, (float*)d_out);
}